// Round 2
// baseline (452.584 us; speedup 1.0000x reference)
//
#include <hip/hip_runtime.h>

#define NN 16384
#define TT 8              // tokens per block
#define NBLK (NN / TT)    // 2048

// out layout (floats): index_q [N,4,128] | index_k [N,128] | weights [N,4]
// offsets: 0 | N*512 | N*512 + N*128

__global__ __launch_bounds__(256) void idxer_kernel(
    const float* __restrict__ q, const float* __restrict__ k,
    const float* __restrict__ v, const float* __restrict__ proj,
    const float* __restrict__ vt, float* __restrict__ out)
{
    const int tid = threadIdx.x;
    const int t0 = blockIdx.x * TT;

    // proj: [n][col] stride 34 -> float2 reads 8B-aligned, conflict-free broadcast
    __shared__ __align__(16) float sproj[32 * 34];
    // v: [token][g*132 + d] pad 132 -> 2-way max on scalar reads (free)
    __shared__ __align__(16) float sv[TT][8 * 132];

    // ---- stage v + proj (all coalesced); one barrier for the whole block ----
    {
        const float4* pv4 = (const float4*)v;
        float4 vbuf[TT];
        #pragma unroll
        for (int t = 0; t < TT; ++t)
            vbuf[t] = pv4[(size_t)(t0 + t) * 256 + tid];
        float pbuf[4];
        #pragma unroll
        for (int i = 0; i < 4; ++i) pbuf[i] = proj[tid + 256 * i];
        #pragma unroll
        for (int i = 0; i < 4; ++i) {
            const int p = tid + 256 * i;
            sproj[(p >> 5) * 34 + (p & 31)] = pbuf[i];
        }
        const int g = tid >> 5;
        const int rem = (tid & 31) * 4;
        #pragma unroll
        for (int t = 0; t < TT; ++t)
            *(float4*)&sv[t][g * 132 + rem] = vbuf[t];
    }
    __syncthreads();

    // ---- index_q: direct global q reads (each element exactly once, full rows
    //      coalesced per wave). 2 tokens per iteration, half-block each. ----
    // thread (group, im, a): n in {a, a+16}; q4[head*32 + im*16 + a] covers
    // d = 4a + 64*im + {0,1,2,3} = {dbase(a), dbase(a+16), dbase(a)+2, dbase(a+16)+2}
    {
        const int half = tid >> 7;
        const int lt = tid & 127;
        const int group = lt >> 5;
        const int im = (lt >> 4) & 1;
        const int a = lt & 15;
        float2* o2 = (float2*)out;
        #pragma unroll 2
        for (int tq = 0; tq < TT / 2; ++tq) {
            const int b = t0 + tq * 2 + half;
            const float4* q4 = (const float4*)(q + (size_t)b * 4096);
            float a0 = 0.f, a1 = 0.f, c0 = 0.f, c1 = 0.f;
            #pragma unroll
            for (int g8 = 0; g8 < 8; ++g8) {
                const float4 qv = q4[(g8 * 4 + group) * 32 + im * 16 + a];
                const float2 pa  = *(const float2*)&sproj[a * 34 + g8 * 2];
                const float2 pa2 = *(const float2*)&sproj[a * 34 + 16 + g8 * 2];
                const float2 pb  = *(const float2*)&sproj[(a + 16) * 34 + g8 * 2];
                const float2 pb2 = *(const float2*)&sproj[(a + 16) * 34 + 16 + g8 * 2];
                a0 += qv.x * pa.x + qv.z * pa2.x;
                a1 += qv.x * pa.y + qv.z * pa2.y;
                c0 += qv.y * pb.x + qv.w * pb2.x;
                c1 += qv.y * pb.y + qv.w * pb2.y;
            }
            o2[(size_t)b * 256 + group * 64 + im * 32 + a]      = make_float2(a0, a1);
            o2[(size_t)b * 256 + group * 64 + im * 32 + a + 16] = make_float2(c0, c1);
        }
    }

    // ---- index_k: all 8 tokens at once (32 threads/token), direct global ----
    {
        const int tsub = tid >> 5;
        const int im = (tid >> 4) & 1;
        const int a = tid & 15;
        const int b = t0 + tsub;
        const float4* k4 = (const float4*)(k + (size_t)b * 1024);
        float a0 = 0.f, a1 = 0.f, c0 = 0.f, c1 = 0.f;
        #pragma unroll
        for (int g = 0; g < 8; ++g) {
            const float4 kv = k4[g * 32 + im * 16 + a];
            const float2 pa  = *(const float2*)&sproj[a * 34 + g * 2];
            const float2 pa2 = *(const float2*)&sproj[a * 34 + 16 + g * 2];
            const float2 pb  = *(const float2*)&sproj[(a + 16) * 34 + g * 2];
            const float2 pb2 = *(const float2*)&sproj[(a + 16) * 34 + 16 + g * 2];
            a0 += kv.x * pa.x + kv.z * pa2.x;
            a1 += kv.x * pa.y + kv.z * pa2.y;
            c0 += kv.y * pb.x + kv.w * pb2.x;
            c1 += kv.y * pb.y + kv.w * pb2.y;
        }
        float2* o2 = (float2*)(out + (size_t)NN * 512);
        o2[(size_t)b * 64 + im * 32 + a]      = make_float2(a0, a1);
        o2[(size_t)b * 64 + im * 32 + a + 16] = make_float2(c0, c1);
    }

    // ---- weights: vt cached in 64 VGPRs (amortized over 8 tokens);
    //      pure in-wave shuffle reduction, no LDS scratch, no barriers ----
    // thread: tid = group*64 + g*8 + s; h = g*4 + group; wave == one group
    {
        const int group = tid >> 6;
        const int g = (tid >> 3) & 7;
        const int s = tid & 7;
        const int h = g * 4 + group;
        const float4* vt4 = (const float4*)vt;   // [H][D] float4 over R
        float4 vtr[16];
        #pragma unroll
        for (int i = 0; i < 16; ++i) vtr[i] = vt4[h * 128 + i * 8 + s];
        float* ow = out + (size_t)NN * 512 + (size_t)NN * 128;
        #pragma unroll 2
        for (int t = 0; t < TT; ++t) {
            float a0 = 0.f, a1 = 0.f, a2 = 0.f, a3 = 0.f;
            #pragma unroll
            for (int i = 0; i < 16; ++i) {
                const float vv = sv[t][g * 132 + i * 8 + s];
                a0 += vv * vtr[i].x; a1 += vv * vtr[i].y;
                a2 += vv * vtr[i].z; a3 += vv * vtr[i].w;
            }
            // sum components over s-octet (must complete before squaring)
            #pragma unroll
            for (int m = 1; m <= 4; m <<= 1) {
                a0 += __shfl_xor(a0, m);
                a1 += __shfl_xor(a1, m);
                a2 += __shfl_xor(a2, m);
                a3 += __shfl_xor(a3, m);
            }
            float ssq = a0 * a0 + a1 * a1 + a2 * a2 + a3 * a3;
            // sum over g (lanes stride 8 within the wave)
            #pragma unroll
            for (int m = 8; m <= 32; m <<= 1) ssq += __shfl_xor(ssq, m);
            if ((tid & 63) == 0) ow[(size_t)(t0 + t) * 4 + group] = sqrtf(ssq);
        }
    }
}

extern "C" void kernel_launch(void* const* d_in, const int* in_sizes, int n_in,
                              void* d_out, int out_size, void* d_ws, size_t ws_size,
                              hipStream_t stream) {
    const float* q    = (const float*)d_in[0];
    const float* k    = (const float*)d_in[1];
    const float* v    = (const float*)d_in[2];
    const float* proj = (const float*)d_in[3];
    const float* vt   = (const float*)d_in[4];
    float* out = (float*)d_out;
    idxer_kernel<<<NBLK, 256, 0, stream>>>(q, k, v, proj, vt, out);
}